// Round 23
// baseline (109.809 us; speedup 1.0000x reference)
//
#include <hip/hip_runtime.h>

// Binarized conv block via i8 MFMA implicit GEMM. == R20 + BARRIER-FREE ==
//   a = sign(x+bias1) in {+1,-1} (i8), zero-padded image [32][58][58][256] i8
//   qk = sign(kernel) in {+1,-1} (i8), packed to FRAGMENT order wf[k64][ch][co]
//   conv == GEMM: C[pixel][co] = sum_k A_im2col[pixel][k] * W[k][co]
//   out = relu(C*scale[co] + shift[co])
//
// R8-R22: every barrier schedule pins at 22-31% MfmaUtil (convoy); R18's
// no-LDS version died of VGPR pressure. R23 = the untried middle: B direct
// from global (R20), A staged into PRIVATE per-wave LDS (16KB/wave, 64KB
// total) -> no cross-wave sharing -> ZERO s_barrier in the K-loop. Waves
// self-sync with counted vmcnt only and drift to cover each other's latency.
// Per step/thread: 8 B loads, 8 A g2l16(s+1), vmcnt(16) (A(s) landed; B(s)
// + A(s+1) stay in flight), ds_read, MFMA. Buffer reuse safe by program
// order (MFMA's lgkm wait precedes next iteration's g2l16 issue).

typedef int v4i __attribute__((ext_vector_type(4)));
typedef unsigned int u32;

#define NB   32
#define HW   56
#define HP   58
#define HP2  (HP*HP)             // 3364
#define CIN  256
#define COUT 256
#define NPIX (NB*HW*HW)          // 100352
#define KTOT 2304
#define BM   128                 // pixels per block
#define BN   128                 // couts per block
#define NSTEP 18                 // K steps of 128 (2 x 64-chunks)
#define NWG  ((NPIX/BM)*(COUT/BN))   // 1568 = 8*196

#define PA_BYTES ((size_t)NB*HP*HP*CIN)     // 27,557,888
#define WT_OFF   PA_BYTES
#define WT_BYTES ((size_t)KTOT*COUT)        // 589,824
#define SC_OFF   (WT_OFF + WT_BYTES)
#define SH_OFF   (SC_OFF + 1024)

__device__ __forceinline__ void g2l16(const void* g, void* l) {
    __builtin_amdgcn_global_load_lds(
        (const __attribute__((address_space(1))) void*)g,
        (__attribute__((address_space(3))) void*)l, 16, 0, 0);
}

// ------- pack activations incl. pad ring: sign(x+bias1) or 0 -> i8 -------
__global__ __launch_bounds__(256) void pack_a_kernel(
    const float* __restrict__ x, const float* __restrict__ b1,
    signed char* __restrict__ pa)
{
    const int lane = threadIdx.x & 63;
    const int pp = blockIdx.x * 4 + (threadIdx.x >> 6);   // padded pixel
    const int n = pp / HP2, r = pp % HP2, ph = r / HP, pw = r % HP;
    const int ci = lane * 4;
    u32 o = 0;
    if (ph >= 1 && ph <= HW && pw >= 1 && pw <= HW) {     // wave-uniform branch
        const int pix = (n * HW + ph - 1) * HW + (pw - 1);
        const float4 xv = *(const float4*)(x + (size_t)pix * CIN + ci);
        const float4 bv = *(const float4*)(b1 + ci);
        o  = (u32)(unsigned char)((xv.x + bv.x >= 0.f) ? 1 : -1);
        o |= (u32)(unsigned char)((xv.y + bv.y >= 0.f) ? 1 : -1) << 8;
        o |= (u32)(unsigned char)((xv.z + bv.z >= 0.f) ? 1 : -1) << 16;
        o |= (u32)(unsigned char)((xv.w + bv.w >= 0.f) ? 1 : -1) << 24;
    }
    *(u32*)(pa + (size_t)pp * CIN + ci) = o;
    // grid = NB*HP*HP/4 = 26912
}

// ------- pack weights into FRAGMENT order: 16B unit (k64,ch,co) -------
__global__ __launch_bounds__(256) void packw_kernel(
    const float* __restrict__ k, signed char* __restrict__ wf)
{
    __shared__ signed char tile[64][256];
    const int t = threadIdx.x, k0 = blockIdx.x * 64;      // k64 = blockIdx.x
    for (int j = 0; j < 64; ++j)
        tile[j][t] = (k[(size_t)(k0 + j) * COUT + t] >= 0.f) ? 1 : -1;
    __syncthreads();
    u32 wd[16];
#pragma unroll
    for (int j = 0; j < 16; ++j) wd[j] = 0;
#pragma unroll
    for (int j = 0; j < 64; ++j)
        wd[j >> 2] |= ((u32)(unsigned char)tile[j][t]) << ((j & 3) * 8);
#pragma unroll
    for (int c = 0; c < 4; ++c)
        *(uint4*)(wf + (((size_t)blockIdx.x * 4 + c) * 256 + t) * 16) =
            make_uint4(wd[4*c], wd[4*c+1], wd[4*c+2], wd[4*c+3]);
    // grid = KTOT/64 = 36
}

// ---------------- fold BN + bias2 ----------------
__global__ __launch_bounds__(256) void bnprep_kernel(
    const float* __restrict__ beta, const float* __restrict__ mean,
    const float* __restrict__ var, const float* __restrict__ b2,
    float* __restrict__ scale, float* __restrict__ shift)
{
    const int t = threadIdx.x;
    const float s = rsqrtf(var[t] + 1e-3f);
    scale[t] = s;
    shift[t] = beta[t] - mean[t] * s + b2[t];
}

// ---------------- i8 implicit-GEMM conv + BN + relu (barrier-free) --------
// 256 thr = 4 INDEPENDENT waves (2x2 grid); wave (vm,vn) owns 64px x 64co:
// acc[4][4], 32 mfma per K-step of 128. A in private per-wave LDS, B direct.
__global__ __launch_bounds__(256, 2) void conv_mfma_kernel(
    const signed char* __restrict__ pa, const signed char* __restrict__ wf,
    const float* __restrict__ scale, const float* __restrict__ shift,
    float* __restrict__ out)
{
    // 4 waves x 2 buf x 2 ksub x 64px x 64B = 64 KB, fully private per wave
    __shared__ signed char L[65536];

    const int t = threadIdx.x, l = t & 63, w = t >> 6;
    const int vm = w >> 1, vn = w & 1;
    // XCD swizzle (1568 = 8 x 196, bijective); co-halves of a tile adjacent
    const int swz  = (blockIdx.x & 7) * (NWG / 8) + (blockIdx.x >> 3);
    const int tile = swz >> 1;
    const int co0  = (swz & 1) << 7;
    const int p0 = tile * BM;
    const int wb = w * 16384;                  // private LDS base

    // A staging: lane l, group j stages 16B of local row rl=j*16+(l>>2),
    // slot l&3, chunk pre-swizzled by ((rl>>1)&3)
    const signed char* abase[4];
#pragma unroll
    for (int j = 0; j < 4; ++j) {
        const int rl = j * 16 + (l >> 2);
        const int p  = p0 + vm * 64 + rl;
        const int n = p / 3136, r = p % 3136, h = r / 56, ww = r % 56;
        const int aswz = (((l & 3) ^ ((rl >> 1) & 3)) << 4);
        abase[j] = pa + ((size_t)(n * HP + h) * HP + ww) * CIN + aswz;
    }

    // A fragment ds_read offsets within (wb + buf*8192 + ks*4096)
    int aoff[4];
#pragma unroll
    for (int pg = 0; pg < 4; ++pg) {
        const int rl = pg * 16 + (l & 15);
        aoff[pg] = rl * 64 + ((((l >> 4) ^ (rl >> 1)) & 3) << 4);
    }
    // B fragment global byte offsets (fragment-ordered panel)
    u32 boffg[4];
#pragma unroll
    for (int cg = 0; cg < 4; ++cg) {
        const int co = co0 + vn * 64 + cg * 16 + (l & 15);
        boffg[cg] = (u32)((((l >> 4) * 256) + co) * 16);
    }

    v4i acc[4][4];
#pragma unroll
    for (int i = 0; i < 4; ++i)
#pragma unroll
        for (int j = 0; j < 4; ++j) acc[i][j] = (v4i){0, 0, 0, 0};

    auto goffA = [&](int k64) {
        const int tap = k64 >> 2, cq = k64 & 3;
        const int ty = tap / 3, tx = tap - ty * 3;
        return ((ty * HP + tx) << 8) + (cq << 6);
    };
    auto STAGE = [&](int buf, int s) {         // 8 g2l16 per thread (private)
#pragma unroll
        for (int ks = 0; ks < 2; ++ks) {
            const int go = goffA(2 * s + ks);
#pragma unroll
            for (int j = 0; j < 4; ++j)
                g2l16(abase[j] + go, &L[wb + buf * 8192 + ks * 4096 + j * 1024]);
        }
    };

    // prologue: A(0) in flight (8 loads)
    STAGE(0, 0);

#pragma unroll 1
    for (int s = 0; s < NSTEP; ++s) {
        const int cur = s & 1, nxt = cur ^ 1;
        const bool pre = (s + 1 < NSTEP);

        // B(s) direct loads (oldest of this step's issues)
        v4i bf[2][4];
#pragma unroll
        for (int ks = 0; ks < 2; ++ks) {
            const u32 kb = (u32)(2 * s + ks) * 16384;
#pragma unroll
            for (int cg = 0; cg < 4; ++cg)
                bf[ks][cg] = *(const v4i*)(wf + kb + boffg[cg]);
        }
        // stage A(s+1) into the other private buffer
        if (pre) STAGE(nxt, s + 1);

        // counted fence: A(s) (oldest 8) landed; B(s) + A(s+1) stay in flight
        if (pre) { asm volatile("s_waitcnt vmcnt(16)" ::: "memory"); }
        else     { asm volatile("s_waitcnt vmcnt(8)"  ::: "memory"); }

        // read af(s) from private cur buffer; compiler adds lgkm before MFMA
        v4i af[2][4];
#pragma unroll
        for (int ks = 0; ks < 2; ++ks)
#pragma unroll
            for (int pg = 0; pg < 4; ++pg)
                af[ks][pg] = *(const v4i*)(&L[wb + cur * 8192 + ks * 4096 + aoff[pg]]);

        __builtin_amdgcn_s_setprio(1);
#pragma unroll
        for (int ks = 0; ks < 2; ++ks)
#pragma unroll
            for (int pg = 0; pg < 4; ++pg)
#pragma unroll
                for (int cg = 0; cg < 4; ++cg)
                    acc[pg][cg] = __builtin_amdgcn_mfma_i32_16x16x64_i8(
                        af[ks][pg], bf[ks][cg], acc[pg][cg], 0, 0, 0);
        __builtin_amdgcn_s_setprio(0);
        // NO barrier: buffers are wave-private; reuse is safe by program
        // order (MFMA's lgkm wait precedes next iteration's g2l16 issue).
    }

    // epilogue: C col = l&15 (co), row = (l>>4)*4 + reg (pixel)   [m89 layout]
#pragma unroll
    for (int cg = 0; cg < 4; ++cg) {
        const int co = co0 + vn * 64 + cg * 16 + (l & 15);
        const float sc = scale[co], sh = shift[co];
#pragma unroll
        for (int pg = 0; pg < 4; ++pg) {
            const int prow0 = p0 + vm * 64 + pg * 16 + (l >> 4) * 4;
#pragma unroll
            for (int rr = 0; rr < 4; ++rr) {
                const float y = (float)acc[pg][cg][rr];
                out[(size_t)(prow0 + rr) * COUT + co] = fmaxf(fmaf(y, sc, sh), 0.f);
            }
        }
    }
}

extern "C" void kernel_launch(void* const* d_in, const int* in_sizes, int n_in,
                              void* d_out, int out_size, void* d_ws, size_t ws_size,
                              hipStream_t stream)
{
    const float* x      = (const float*)d_in[0];
    const float* bias1  = (const float*)d_in[1];
    const float* kernel = (const float*)d_in[2];
    const float* bn_beta = (const float*)d_in[3];
    const float* bn_mean = (const float*)d_in[4];
    const float* bn_var  = (const float*)d_in[5];
    const float* bias2   = (const float*)d_in[6];
    float* out = (float*)d_out;

    signed char* pa  = (signed char*)d_ws;                // padded i8 image
    signed char* wfp = (signed char*)d_ws + WT_OFF;       // fragment-ordered W
    float* scale = (float*)((char*)d_ws + SC_OFF);
    float* shift = (float*)((char*)d_ws + SH_OFF);

    pack_a_kernel<<<dim3(NB * HP2 / 4), dim3(256), 0, stream>>>(x, bias1, pa);
    packw_kernel<<<dim3(KTOT / 64), dim3(256), 0, stream>>>(kernel, wfp);
    bnprep_kernel<<<dim3(1), dim3(256), 0, stream>>>(bn_beta, bn_mean, bn_var, bias2,
                                                     scale, shift);
    conv_mfma_kernel<<<dim3(NWG), dim3(256), 0, stream>>>(pa, wfp, scale, shift, out);
}

// Round 24
// 99.105 us; speedup vs baseline: 1.1080x; 1.1080x over previous
//
#include <hip/hip_runtime.h>

// Binarized conv block via i8 MFMA implicit GEMM.  == R20, session best ==
//   a = sign(x+bias1) in {+1,-1} (i8), zero-padded image [32][58][58][256] i8
//   qk = sign(kernel) in {+1,-1} (i8), packed to FRAGMENT order wf[k64][ch][co]
//   conv == GEMM: C[pixel][co] = sum_k A_im2col[pixel][k] * W[k][co]
//   out = relu(C*scale[co] + shift[co])   (folded BN + bias2)
//
// Final ledger (R3-R23): popcount path 143us (v_bcnt HW floor); 13 MFMA
// structures — 2-phase/8-phase/3-deep counted-vmcnt/4-wave/8-wave/3 tile
// shapes/zero-LDS direct-reg/B-reg-prefetch/barrier-free — ALL pin at
// 22-31% MfmaUtil. The limit is the per-wave dependent chain (vmcnt ->
// ds_read -> lgkm -> MFMA) at ~2 waves/SIMD; every independence-adding
// variant trades away more than it gains. Best = THIS: BK=128 (32-MFMA
// clusters, 18 steps), 2x2 wave grid, A via LDS (g2l16 + chunk-XOR src
// swizzle), B DIRECT global->VGPR from fragment-ordered L2-resident panel,
// stage-early + one vmcnt(0)+barrier per step, setprio, XCD swizzle.
// Measured: conv 80us @ 31% MfmaUtil, total 99.0us, absmax 0.0.

typedef int v4i __attribute__((ext_vector_type(4)));
typedef unsigned int u32;

#define NB   32
#define HW   56
#define HP   58
#define HP2  (HP*HP)             // 3364
#define CIN  256
#define COUT 256
#define NPIX (NB*HW*HW)          // 100352
#define KTOT 2304
#define BM   128                 // pixels per block
#define BN   128                 // couts per block
#define NSTEP 18                 // K steps of 128 (2 x 64-chunks)
#define NWG  ((NPIX/BM)*(COUT/BN))   // 1568 = 8*196

#define PA_BYTES ((size_t)NB*HP*HP*CIN)     // 27,557,888
#define WT_OFF   PA_BYTES
#define WT_BYTES ((size_t)KTOT*COUT)        // 589,824
#define SC_OFF   (WT_OFF + WT_BYTES)
#define SH_OFF   (SC_OFF + 1024)

__device__ __forceinline__ void g2l16(const void* g, void* l) {
    __builtin_amdgcn_global_load_lds(
        (const __attribute__((address_space(1))) void*)g,
        (__attribute__((address_space(3))) void*)l, 16, 0, 0);
}

// ------- pack activations incl. pad ring: sign(x+bias1) or 0 -> i8 -------
__global__ __launch_bounds__(256) void pack_a_kernel(
    const float* __restrict__ x, const float* __restrict__ b1,
    signed char* __restrict__ pa)
{
    const int lane = threadIdx.x & 63;
    const int pp = blockIdx.x * 4 + (threadIdx.x >> 6);   // padded pixel
    const int n = pp / HP2, r = pp % HP2, ph = r / HP, pw = r % HP;
    const int ci = lane * 4;
    u32 o = 0;
    if (ph >= 1 && ph <= HW && pw >= 1 && pw <= HW) {     // wave-uniform branch
        const int pix = (n * HW + ph - 1) * HW + (pw - 1);
        const float4 xv = *(const float4*)(x + (size_t)pix * CIN + ci);
        const float4 bv = *(const float4*)(b1 + ci);
        o  = (u32)(unsigned char)((xv.x + bv.x >= 0.f) ? 1 : -1);
        o |= (u32)(unsigned char)((xv.y + bv.y >= 0.f) ? 1 : -1) << 8;
        o |= (u32)(unsigned char)((xv.z + bv.z >= 0.f) ? 1 : -1) << 16;
        o |= (u32)(unsigned char)((xv.w + bv.w >= 0.f) ? 1 : -1) << 24;
    }
    *(u32*)(pa + (size_t)pp * CIN + ci) = o;
    // grid = NB*HP*HP/4 = 26912
}

// ------- pack weights into FRAGMENT order: 16B unit (k64,ch,co) -------
// unit address = ((k64*4 + ch)*256 + co)*16 ; contains W k-values
// k64*64 + ch*16 .. +16 for output co (exactly the bytes the old LDS
// fragment read produced for lane group ch).
__global__ __launch_bounds__(256) void packw_kernel(
    const float* __restrict__ k, signed char* __restrict__ wf)
{
    __shared__ signed char tile[64][256];
    const int t = threadIdx.x, k0 = blockIdx.x * 64;      // k64 = blockIdx.x
    for (int j = 0; j < 64; ++j)
        tile[j][t] = (k[(size_t)(k0 + j) * COUT + t] >= 0.f) ? 1 : -1;
    __syncthreads();
    u32 wd[16];
#pragma unroll
    for (int j = 0; j < 16; ++j) wd[j] = 0;
#pragma unroll
    for (int j = 0; j < 64; ++j)
        wd[j >> 2] |= ((u32)(unsigned char)tile[j][t]) << ((j & 3) * 8);
#pragma unroll
    for (int c = 0; c < 4; ++c)
        *(uint4*)(wf + (((size_t)blockIdx.x * 4 + c) * 256 + t) * 16) =
            make_uint4(wd[4*c], wd[4*c+1], wd[4*c+2], wd[4*c+3]);
    // grid = KTOT/64 = 36
}

// ---------------- fold BN + bias2 ----------------
__global__ __launch_bounds__(256) void bnprep_kernel(
    const float* __restrict__ beta, const float* __restrict__ mean,
    const float* __restrict__ var, const float* __restrict__ b2,
    float* __restrict__ scale, float* __restrict__ shift)
{
    const int t = threadIdx.x;
    const float s = rsqrtf(var[t] + 1e-3f);
    scale[t] = s;
    shift[t] = beta[t] - mean[t] * s + b2[t];
}

// ---------------- i8 implicit-GEMM conv + BN + relu ----------------
// 256 thr = 2x2 wave grid; block = 128px x 128co; wave (vm,vn) owns
// 64px x 64co: acc[4][4], 32 mfma per K-step of 128. A via LDS (R14 path),
// B direct global->VGPR from the fragment-ordered L2-resident panel.
__global__ __launch_bounds__(256, 2) void conv_mfma_kernel(
    const signed char* __restrict__ pa, const signed char* __restrict__ wf,
    const float* __restrict__ scale, const float* __restrict__ shift,
    float* __restrict__ out)
{
    // per buffer: A = 2ksub x 128px x 64B = 16KB
    __shared__ signed char L[2][16384];

    const int t = threadIdx.x, l = t & 63, v = t >> 6;
    const int vm = v >> 1, vn = v & 1;
    // XCD swizzle (1568 = 8 x 196, bijective); co-halves of a tile adjacent
    const int swz  = (blockIdx.x & 7) * (NWG / 8) + (blockIdx.x >> 3);
    const int tile = swz >> 1;
    const int co0  = (swz & 1) << 7;
    const int p0 = tile * BM;

    // A staging: thread t stages 16B slot (t&3) of pixel q=(t>>2)+i*64
    const signed char* abase[2];
#pragma unroll
    for (int i = 0; i < 2; ++i) {
        const int q = (t >> 2) + i * 64;
        const int p = p0 + q;
        const int n = p / 3136, r = p % 3136, h = r / 56, w = r % 56;
        const int aswz = (((t & 3) ^ ((q >> 1) & 3)) << 4);  // source pre-swizzle
        abase[i] = pa + ((size_t)(n * HP + h) * HP + w) * CIN + aswz;
    }

    // A fragment ds_read offsets (swizzled reads match pre-swizzled src)
    int aoff[4];
#pragma unroll
    for (int pg = 0; pg < 4; ++pg) {
        const int row = vm * 64 + pg * 16 + (l & 15);
        aoff[pg] = row * 64 + ((((l >> 4) ^ (row >> 1)) & 3) << 4);
    }
    // B fragment global byte offsets (fragment-ordered panel)
    u32 boffg[4];
#pragma unroll
    for (int cg = 0; cg < 4; ++cg) {
        const int co = co0 + vn * 64 + cg * 16 + (l & 15);
        boffg[cg] = (u32)((((l >> 4) * 256) + co) * 16);
    }

    v4i acc[4][4];
#pragma unroll
    for (int i = 0; i < 4; ++i)
#pragma unroll
        for (int j = 0; j < 4; ++j) acc[i][j] = (v4i){0, 0, 0, 0};

    auto goffA = [&](int k64) {
        const int tap = k64 >> 2, cq = k64 & 3;
        const int ty = tap / 3, tx = tap - ty * 3;
        return ((ty * HP + tx) << 8) + (cq << 6);
    };
    auto STAGE = [&](int buf, int s) {         // 4 g2l16 per thread (A only)
#pragma unroll
        for (int ks = 0; ks < 2; ++ks) {
            const int k64 = 2 * s + ks;
            const int go = goffA(k64);
            g2l16(abase[0] + go, &L[buf][ks * 8192 + v * 1024]);
            g2l16(abase[1] + go, &L[buf][ks * 8192 + 4096 + v * 1024]);
        }
    };

    // prologue
    STAGE(0, 0);
    asm volatile("s_waitcnt vmcnt(0)" ::: "memory");
    __builtin_amdgcn_s_barrier();

#pragma unroll 1
    for (int s = 0; s < NSTEP; ++s) {
        const int cur = s & 1, nxt = cur ^ 1;
        const signed char* Lc = &L[cur][0];
        if (s + 1 < NSTEP) STAGE(nxt, s + 1);  // issue early; lands by step end
        // B fragments: direct global (L2-hot), issued with the A ds_reads
        v4i af[2][4], bf[2][4];
#pragma unroll
        for (int ks = 0; ks < 2; ++ks) {
            const u32 kbase = (u32)(2 * s + ks) * 16384;
#pragma unroll
            for (int cg = 0; cg < 4; ++cg)
                bf[ks][cg] = *(const v4i*)(wf + kbase + boffg[cg]);
#pragma unroll
            for (int pg = 0; pg < 4; ++pg)
                af[ks][pg] = *(const v4i*)(Lc + ks * 8192 + aoff[pg]);
        }
        __builtin_amdgcn_s_setprio(1);
#pragma unroll
        for (int ks = 0; ks < 2; ++ks)
#pragma unroll
            for (int pg = 0; pg < 4; ++pg)
#pragma unroll
                for (int cg = 0; cg < 4; ++cg)
                    acc[pg][cg] = __builtin_amdgcn_mfma_i32_16x16x64_i8(
                        af[ks][pg], bf[ks][cg], acc[pg][cg], 0, 0, 0);
        __builtin_amdgcn_s_setprio(0);
        // stage(s+1) landed + all waves done reading cur (reads precede MFMAs)
        asm volatile("s_waitcnt vmcnt(0)" ::: "memory");
        __builtin_amdgcn_s_barrier();
    }

    // epilogue: C col = l&15 (co), row = (l>>4)*4 + reg (pixel)   [m89 layout]
#pragma unroll
    for (int cg = 0; cg < 4; ++cg) {
        const int co = co0 + vn * 64 + cg * 16 + (l & 15);
        const float sc = scale[co], sh = shift[co];
#pragma unroll
        for (int pg = 0; pg < 4; ++pg) {
            const int prow0 = p0 + vm * 64 + pg * 16 + (l >> 4) * 4;
#pragma unroll
            for (int rr = 0; rr < 4; ++rr) {
                const float y = (float)acc[pg][cg][rr];
                out[(size_t)(prow0 + rr) * COUT + co] = fmaxf(fmaf(y, sc, sh), 0.f);
            }
        }
    }
}

extern "C" void kernel_launch(void* const* d_in, const int* in_sizes, int n_in,
                              void* d_out, int out_size, void* d_ws, size_t ws_size,
                              hipStream_t stream)
{
    const float* x      = (const float*)d_in[0];
    const float* bias1  = (const float*)d_in[1];
    const float* kernel = (const float*)d_in[2];
    const float* bn_beta = (const float*)d_in[3];
    const float* bn_mean = (const float*)d_in[4];
    const float* bn_var  = (const float*)d_in[5];
    const float* bias2   = (const float*)d_in[6];
    float* out = (float*)d_out;

    signed char* pa  = (signed char*)d_ws;                // padded i8 image
    signed char* wfp = (signed char*)d_ws + WT_OFF;       // fragment-ordered W
    float* scale = (float*)((char*)d_ws + SC_OFF);
    float* shift = (float*)((char*)d_ws + SH_OFF);

    pack_a_kernel<<<dim3(NB * HP2 / 4), dim3(256), 0, stream>>>(x, bias1, pa);
    packw_kernel<<<dim3(KTOT / 64), dim3(256), 0, stream>>>(kernel, wfp);
    bnprep_kernel<<<dim3(1), dim3(256), 0, stream>>>(bn_beta, bn_mean, bn_var, bias2,
                                                     scale, shift);
    conv_mfma_kernel<<<dim3(NWG), dim3(256), 0, stream>>>(pa, wfp, scale, shift, out);
}